// Round 1
// baseline (5875.599 us; speedup 1.0000x reference)
//
#include <hip/hip_runtime.h>
#include <stdint.h>

// Problem constants (from reference)
#define B_DIM 4
#define T_DIM 512
#define NTOK  2048          // B*T
#define H_DIM 2048
#define V_DIM 32000
#define TM    128
#define TN    128
#define BK    32
#define NCHUNK (V_DIM / TN) // 250
#define NTILE  (NTOK / TM)  // 16
#define BETA   0.1f
#define IGNORE_INDEX (-100)

typedef _Float16 f16;
typedef _Float16 half8 __attribute__((ext_vector_type(8)));
typedef float    f32x4 __attribute__((ext_vector_type(4)));

// ---------------------------------------------------------------- fp32 -> fp16
__global__ __launch_bounds__(256) void cvt_f32_f16(const float* __restrict__ src,
                                                   f16* __restrict__ dst, int n) {
    int i = (blockIdx.x * 256 + threadIdx.x) * 8;
    if (i + 8 > n) return;
    float4 v0 = *(const float4*)(src + i);
    float4 v1 = *(const float4*)(src + i + 4);
    half8 h = { (f16)v0.x, (f16)v0.y, (f16)v0.z, (f16)v0.w,
                (f16)v1.x, (f16)v1.y, (f16)v1.z, (f16)v1.w };
    *(half8*)(dst + i) = h;
}

// ---------------------------------------------------------------- GEMM + online LSE partials
// C[m][n] = sum_k X[m][k] * W[n][k]   (NT gemm, both row-major with K contiguous)
// Per block: 128 tokens x 128 vocab, K=2048. Writes per-(token,chunk) max & sumexp
// partials and the target logit (if target falls in this chunk).
template <bool DIRECT>
__global__ __launch_bounds__(256) void gemm_lse(
    const void* __restrict__ x0, const void* __restrict__ x1,
    const void* __restrict__ w0, const void* __restrict__ w1,
    const int* __restrict__ y,
    float* __restrict__ pM, float* __restrict__ pS,
    float* __restrict__ tokL)
{
    const int tile  = blockIdx.x;   // 0..15   (fastest: consecutive blocks share W chunk)
    const int chunk = blockIdx.y;   // 0..249
    const int model = blockIdx.z;   // 0..1
    const void* Xp = model ? x1 : x0;
    const void* Wp = model ? w1 : w0;

    const int tid  = threadIdx.x;
    const int lane = tid & 63;
    const int wave = tid >> 6;
    const int wm   = wave >> 1;     // 0..1: which 64-row half
    const int wn   = wave & 1;      // 0..1: which 64-col half

    __shared__ __align__(16) f16 As[TM * BK];  // 8 KB
    __shared__ __align__(16) f16 Bs[TN * BK];  // 8 KB
    __shared__ float redM[TM][2];
    __shared__ float redS[TM][2];
    __shared__ int   ys[TM];

    if (tid < TM) ys[tid] = y[tile * TM + tid];

    f32x4 acc[4][4];
#pragma unroll
    for (int i = 0; i < 4; ++i)
#pragma unroll
        for (int j = 0; j < 4; ++j) acc[i][j] = (f32x4){0.f, 0.f, 0.f, 0.f};

    const int rowA0 = tile * TM;
    const int rowB0 = chunk * TN;
    const int quad8 = (lane >> 4) * 8;   // k-offset of this lane's fragment

    for (int k0 = 0; k0 < H_DIM; k0 += BK) {
        if (DIRECT) {
            const f16* Xg = (const f16*)Xp;
            const f16* Wg = (const f16*)Wp;
#pragma unroll
            for (int i = 0; i < 2; ++i) {
                int idx = i * 256 + tid;
                int r = idx >> 2, c = (idx & 3) * 8;
                __builtin_amdgcn_global_load_lds(
                    (const __attribute__((address_space(1))) unsigned int*)(Xg + (size_t)(rowA0 + r) * H_DIM + k0 + c),
                    (__attribute__((address_space(3))) unsigned int*)(As + idx * 8),
                    16, 0, 0);
            }
#pragma unroll
            for (int i = 0; i < 2; ++i) {
                int idx = i * 256 + tid;
                int r = idx >> 2, c = (idx & 3) * 8;
                __builtin_amdgcn_global_load_lds(
                    (const __attribute__((address_space(1))) unsigned int*)(Wg + (size_t)(rowB0 + r) * H_DIM + k0 + c),
                    (__attribute__((address_space(3))) unsigned int*)(Bs + idx * 8),
                    16, 0, 0);
            }
        } else {
            const float* Xg = (const float*)Xp;
            const float* Wg = (const float*)Wp;
#pragma unroll
            for (int i = 0; i < 2; ++i) {
                int idx = i * 256 + tid;
                int r = idx >> 2, c = (idx & 3) * 8;
                const float* g = Xg + (size_t)(rowA0 + r) * H_DIM + k0 + c;
                float4 v0 = *(const float4*)g;
                float4 v1 = *(const float4*)(g + 4);
                half8 h = { (f16)v0.x, (f16)v0.y, (f16)v0.z, (f16)v0.w,
                            (f16)v1.x, (f16)v1.y, (f16)v1.z, (f16)v1.w };
                *(half8*)(As + idx * 8) = h;
            }
#pragma unroll
            for (int i = 0; i < 2; ++i) {
                int idx = i * 256 + tid;
                int r = idx >> 2, c = (idx & 3) * 8;
                const float* g = Wg + (size_t)(rowB0 + r) * H_DIM + k0 + c;
                float4 v0 = *(const float4*)g;
                float4 v1 = *(const float4*)(g + 4);
                half8 h = { (f16)v0.x, (f16)v0.y, (f16)v0.z, (f16)v0.w,
                            (f16)v1.x, (f16)v1.y, (f16)v1.z, (f16)v1.w };
                *(half8*)(Bs + idx * 8) = h;
            }
        }
        __syncthreads();

        half8 af[4], bfr[4];
#pragma unroll
        for (int i = 0; i < 4; ++i)
            af[i] = *(const half8*)(As + (wm * 64 + i * 16 + (lane & 15)) * BK + quad8);
#pragma unroll
        for (int j = 0; j < 4; ++j)
            bfr[j] = *(const half8*)(Bs + (wn * 64 + j * 16 + (lane & 15)) * BK + quad8);
#pragma unroll
        for (int i = 0; i < 4; ++i)
#pragma unroll
            for (int j = 0; j < 4; ++j)
                acc[i][j] = __builtin_amdgcn_mfma_f32_16x16x32_f16(af[i], bfr[j], acc[i][j], 0, 0, 0);
        __syncthreads();
    }

    // ---- epilogue ----
    // C/D layout: col = lane&15 (vocab), row = (lane>>4)*4 + reg (token)
    // 1) target logit extraction
#pragma unroll
    for (int i = 0; i < 4; ++i) {
#pragma unroll
        for (int r = 0; r < 4; ++r) {
            int rl = wm * 64 + i * 16 + ((lane >> 4) << 2) + r;
            int t = ys[rl];
            int trel = t - (rowB0 + wn * 64);
            if (trel >= 0 && trel < 64) {
                int j = trel >> 4;
                if ((trel & 15) == (lane & 15))
                    tokL[model * NTOK + rowA0 + rl] = acc[i][j][r];
            }
        }
    }

    // 2) per-row (max, sumexp) over this wave's 64 columns, then combine halves
#pragma unroll
    for (int i = 0; i < 4; ++i) {
#pragma unroll
        for (int r = 0; r < 4; ++r) {
            float mx = fmaxf(fmaxf(acc[i][0][r], acc[i][1][r]),
                             fmaxf(acc[i][2][r], acc[i][3][r]));
            for (int m = 1; m < 16; m <<= 1) mx = fmaxf(mx, __shfl_xor(mx, m, 64));
            float s = 0.f;
#pragma unroll
            for (int j = 0; j < 4; ++j) s += __expf(acc[i][j][r] - mx);
            for (int m = 1; m < 16; m <<= 1) s += __shfl_xor(s, m, 64);
            if ((lane & 15) == 0) {
                int rl = wm * 64 + i * 16 + ((lane >> 4) << 2) + r;
                redM[rl][wn] = mx;
                redS[rl][wn] = s;
            }
        }
    }
    __syncthreads();
    if (tid < TM) {
        float m0 = redM[tid][0], m1 = redM[tid][1];
        float s0 = redS[tid][0], s1 = redS[tid][1];
        float M = fmaxf(m0, m1);
        float S = s0 * __expf(m0 - M) + s1 * __expf(m1 - M);
        size_t o = ((size_t)model * NCHUNK + chunk) * NTOK + rowA0 + tid;
        pM[o] = M;
        pS[o] = S;
    }
}

// ---------------------------------------------------------------- combine chunk partials -> per-token logp
__global__ __launch_bounds__(256) void lse_reduce(const float* __restrict__ pM,
                                                  const float* __restrict__ pS,
                                                  const float* __restrict__ tokL,
                                                  const int* __restrict__ y,
                                                  float* __restrict__ logp) {
    int g = blockIdx.x * 256 + threadIdx.x;
    if (g >= 2 * NTOK) return;
    int model = g >> 11;
    int token = g & (NTOK - 1);
    float M = -1e30f, S = 0.f;
    for (int c = 0; c < NCHUNK; ++c) {
        size_t o = ((size_t)model * NCHUNK + c) * NTOK + token;
        float m = pM[o], s = pS[o];
        if (m > M) { S = S * __expf(M - m) + s; M = m; }
        else       { S += s * __expf(m - M); }
    }
    float lse = M + logf(S);
    int t = y[token];
    logp[g] = (t == IGNORE_INDEX) ? 0.f : (tokL[g] - lse);
}

// ---------------------------------------------------------------- final KTO scalar
__device__ __forceinline__ float sigf(float z) { return 1.f / (1.f + expf(-z)); }

__global__ void final_loss(const float* __restrict__ logp,
                           const int* __restrict__ y,
                           float* __restrict__ out) {
    int lane = threadIdx.x;  // 64 threads, one wave
    float avg[2][4];
    for (int model = 0; model < 2; ++model)
        for (int b = 0; b < 4; ++b) {
            float s = 0.f, c = 0.f;
            for (int t = lane; t < T_DIM; t += 64) {
                int token = b * T_DIM + t;
                if (y[token] != IGNORE_INDEX) { s += logp[model * NTOK + token]; c += 1.f; }
            }
            for (int m = 1; m < 64; m <<= 1) {
                s += __shfl_xor(s, m, 64);
                c += __shfl_xor(c, m, 64);
            }
            avg[model][b] = s / c;
        }
    if (lane == 0) {
        float loss = 0.f;
        for (int b = 0; b < 2; ++b) {                    // chosen
            float lr = avg[0][b] - avg[1][b];
            loss += 1.f - sigf(BETA * lr);
        }
        for (int b = 2; b < 4; ++b) {                    // rejected
            float lr = avg[0][b] - avg[1][b];
            loss += 1.f - sigf(-BETA * lr);
        }
        out[0] = loss * 0.5f;                            // / half (half = 2)
    }
}

// ---------------------------------------------------------------- launch
extern "C" void kernel_launch(void* const* d_in, const int* in_sizes, int n_in,
                              void* d_out, int out_size, void* d_ws, size_t ws_size,
                              hipStream_t stream) {
    const float* x  = (const float*)d_in[0];
    const float* rx = (const float*)d_in[1];
    const int*   y  = (const int*)d_in[2];
    const float* W  = (const float*)d_in[3];
    const float* rW = (const float*)d_in[4];
    float* out = (float*)d_out;

    const size_t nX = (size_t)NTOK * H_DIM;   // 4,194,304
    const size_t nW = (size_t)V_DIM * H_DIM;  // 65,536,000

    char* p = (char*)d_ws;
    float* pM   = (float*)p; p += (size_t)2 * NCHUNK * NTOK * 4;
    float* pS   = (float*)p; p += (size_t)2 * NCHUNK * NTOK * 4;
    float* tokL = (float*)p; p += (size_t)2 * NTOK * 4;
    float* logp = (float*)p; p += (size_t)2 * NTOK * 4;
    size_t base = (size_t)(p - (char*)d_ws);
    size_t need_fast = base + 2 * nX * 2 + 2 * nW * 2;

    dim3 grid(NTILE, NCHUNK, 2);
    if (ws_size >= need_fast) {
        f16* xb  = (f16*)p; p += nX * 2;
        f16* rxb = (f16*)p; p += nX * 2;
        f16* wb  = (f16*)p; p += nW * 2;
        f16* rwb = (f16*)p; p += nW * 2;
        cvt_f32_f16<<<(int)(nX / 8 / 256), 256, 0, stream>>>(x,  xb,  (int)nX);
        cvt_f32_f16<<<(int)(nX / 8 / 256), 256, 0, stream>>>(rx, rxb, (int)nX);
        cvt_f32_f16<<<(int)(nW / 8 / 256), 256, 0, stream>>>(W,  wb,  (int)nW);
        cvt_f32_f16<<<(int)(nW / 8 / 256), 256, 0, stream>>>(rW, rwb, (int)nW);
        gemm_lse<true><<<grid, 256, 0, stream>>>(xb, rxb, wb, rwb, y, pM, pS, tokL);
    } else {
        gemm_lse<false><<<grid, 256, 0, stream>>>(x, rx, W, rW, y, pM, pS, tokL);
    }
    lse_reduce<<<16, 256, 0, stream>>>(pM, pS, tokL, y, logp);
    final_loss<<<1, 64, 0, stream>>>(logp, y, out);
}

// Round 2
// 1899.622 us; speedup vs baseline: 3.0930x; 3.0930x over previous
//
#include <hip/hip_runtime.h>
#include <stdint.h>

// Problem constants (from reference)
#define B_DIM 4
#define T_DIM 512
#define NTOK  2048          // B*T
#define H_DIM 2048
#define V_DIM 32000
#define TM    128
#define TN    128
#define BK    32
#define NCHUNK (V_DIM / TN) // 250
#define NTILE  (NTOK / TM)  // 16
#define BETA   0.1f
#define IGNORE_INDEX (-100)

typedef _Float16 f16;
typedef _Float16 half8 __attribute__((ext_vector_type(8)));
typedef float    f32x4 __attribute__((ext_vector_type(4)));

// ---------------------------------------------------------------- fp32 -> fp16
__global__ __launch_bounds__(256) void cvt_f32_f16(const float* __restrict__ src,
                                                   f16* __restrict__ dst, int n) {
    int i = (blockIdx.x * 256 + threadIdx.x) * 8;
    if (i + 8 > n) return;
    float4 v0 = *(const float4*)(src + i);
    float4 v1 = *(const float4*)(src + i + 4);
    half8 h = { (f16)v0.x, (f16)v0.y, (f16)v0.z, (f16)v0.w,
                (f16)v1.x, (f16)v1.y, (f16)v1.z, (f16)v1.w };
    *(half8*)(dst + i) = h;
}

// ---------------------------------------------------------------- GEMM + online LSE partials
// C[m][n] = sum_k X[m][k] * W[n][k]   (NT gemm, both row-major, K contiguous)
// LDS tile layout: [kchunk(4)][row(128)][8 halves] so fragment reads by the 16
// lanes of a quad-group touch contiguous 16B cells (2-way bank alias = free).
template <bool DIRECT>
__global__ __launch_bounds__(256, 1) void gemm_lse(
    const void* __restrict__ x0, const void* __restrict__ x1,
    const void* __restrict__ w0, const void* __restrict__ w1,
    const int* __restrict__ y,
    float* __restrict__ pM, float* __restrict__ pS,
    float* __restrict__ tokL)
{
    const int tile  = blockIdx.x;   // 0..15
    const int chunk = blockIdx.y;   // 0..249
    const int model = blockIdx.z;   // 0..1
    const void* Xp = model ? x1 : x0;
    const void* Wp = model ? w1 : w0;

    const int tid  = threadIdx.x;
    const int lane = tid & 63;
    const int wave = tid >> 6;
    const int wm   = wave >> 1;     // 0..1: which 64-row half (tokens)
    const int wn   = wave & 1;      // 0..1: which 64-col half (vocab)

    __shared__ __align__(16) f16 As[4][TM][8];  // 8 KB  [kchunk][row][8]
    __shared__ __align__(16) f16 Bs[4][TN][8];  // 8 KB
    __shared__ float redM[TM][2];
    __shared__ float redS[TM][2];
    __shared__ int   ys[TM];

    if (tid < TM) ys[tid] = y[tile * TM + tid];

    f32x4 acc[4][4];
#pragma unroll
    for (int i = 0; i < 4; ++i)
#pragma unroll
        for (int j = 0; j < 4; ++j) acc[i][j] = (f32x4){0.f, 0.f, 0.f, 0.f};

    const int rowA0 = tile * TM;
    const int rowB0 = chunk * TN;
    const int kc    = lane >> 4;    // k-chunk (0..3) of this lane's fragment

    for (int k0 = 0; k0 < H_DIM; k0 += BK) {
        if (DIRECT) {
            const f16* Xg = (const f16*)Xp;
            const f16* Wg = (const f16*)Wp;
#pragma unroll
            for (int i = 0; i < 2; ++i) {
                int idx = i * 256 + tid;          // slot = c*128 + r
                int c = idx >> 7, r = idx & 127;
                __builtin_amdgcn_global_load_lds(
                    (const __attribute__((address_space(1))) unsigned int*)(Xg + (size_t)(rowA0 + r) * H_DIM + k0 + c * 8),
                    (__attribute__((address_space(3))) unsigned int*)(&As[0][0][0] + idx * 8),
                    16, 0, 0);
            }
#pragma unroll
            for (int i = 0; i < 2; ++i) {
                int idx = i * 256 + tid;
                int c = idx >> 7, r = idx & 127;
                __builtin_amdgcn_global_load_lds(
                    (const __attribute__((address_space(1))) unsigned int*)(Wg + (size_t)(rowB0 + r) * H_DIM + k0 + c * 8),
                    (__attribute__((address_space(3))) unsigned int*)(&Bs[0][0][0] + idx * 8),
                    16, 0, 0);
            }
        } else {
            const float* Xg = (const float*)Xp;
            const float* Wg = (const float*)Wp;
#pragma unroll
            for (int i = 0; i < 2; ++i) {
                int idx = i * 256 + tid;
                int c = idx >> 7, r = idx & 127;
                const float* g = Xg + (size_t)(rowA0 + r) * H_DIM + k0 + c * 8;
                float4 v0 = *(const float4*)g;
                float4 v1 = *(const float4*)(g + 4);
                half8 h = { (f16)v0.x, (f16)v0.y, (f16)v0.z, (f16)v0.w,
                            (f16)v1.x, (f16)v1.y, (f16)v1.z, (f16)v1.w };
                *(half8*)(&As[0][0][0] + idx * 8) = h;
            }
#pragma unroll
            for (int i = 0; i < 2; ++i) {
                int idx = i * 256 + tid;
                int c = idx >> 7, r = idx & 127;
                const float* g = Wg + (size_t)(rowB0 + r) * H_DIM + k0 + c * 8;
                float4 v0 = *(const float4*)g;
                float4 v1 = *(const float4*)(g + 4);
                half8 h = { (f16)v0.x, (f16)v0.y, (f16)v0.z, (f16)v0.w,
                            (f16)v1.x, (f16)v1.y, (f16)v1.z, (f16)v1.w };
                *(half8*)(&Bs[0][0][0] + idx * 8) = h;
            }
        }
        __syncthreads();

        half8 af[4], bfr[4];
#pragma unroll
        for (int i = 0; i < 4; ++i)
            af[i] = *(const half8*)As[kc][wm * 64 + i * 16 + (lane & 15)];
#pragma unroll
        for (int j = 0; j < 4; ++j)
            bfr[j] = *(const half8*)Bs[kc][wn * 64 + j * 16 + (lane & 15)];
#pragma unroll
        for (int i = 0; i < 4; ++i)
#pragma unroll
            for (int j = 0; j < 4; ++j)
                acc[i][j] = __builtin_amdgcn_mfma_f32_16x16x32_f16(af[i], bfr[j], acc[i][j], 0, 0, 0);
        __syncthreads();
    }

    // ---- epilogue ----
    // C/D layout: col = lane&15 (vocab), row = (lane>>4)*4 + reg (token)
    // 1) target logit extraction — ALL acc indices compile-time constant
    //    (runtime indexing demotes acc to scratch: 30 GB writeback bug, R1)
#pragma unroll
    for (int i = 0; i < 4; ++i) {
#pragma unroll
        for (int r = 0; r < 4; ++r) {
            int rl = wm * 64 + i * 16 + ((lane >> 4) << 2) + r;
            int t = ys[rl];
            int trel = t - (rowB0 + wn * 64);
#pragma unroll
            for (int j = 0; j < 4; ++j) {
                if (trel == j * 16 + (lane & 15))
                    tokL[model * NTOK + rowA0 + rl] = acc[i][j][r];
            }
        }
    }

    // 2) per-row (max, sumexp) over this wave's 64 columns, then combine halves
#pragma unroll
    for (int i = 0; i < 4; ++i) {
#pragma unroll
        for (int r = 0; r < 4; ++r) {
            float mx = fmaxf(fmaxf(acc[i][0][r], acc[i][1][r]),
                             fmaxf(acc[i][2][r], acc[i][3][r]));
            for (int m = 1; m < 16; m <<= 1) mx = fmaxf(mx, __shfl_xor(mx, m, 64));
            float s = 0.f;
#pragma unroll
            for (int j = 0; j < 4; ++j) s += __expf(acc[i][j][r] - mx);
            for (int m = 1; m < 16; m <<= 1) s += __shfl_xor(s, m, 64);
            if ((lane & 15) == 0) {
                int rl = wm * 64 + i * 16 + ((lane >> 4) << 2) + r;
                redM[rl][wn] = mx;
                redS[rl][wn] = s;
            }
        }
    }
    __syncthreads();
    if (tid < TM) {
        float m0 = redM[tid][0], m1 = redM[tid][1];
        float s0 = redS[tid][0], s1 = redS[tid][1];
        float M = fmaxf(m0, m1);
        float S = s0 * __expf(m0 - M) + s1 * __expf(m1 - M);
        size_t o = ((size_t)model * NCHUNK + chunk) * NTOK + rowA0 + tid;
        pM[o] = M;
        pS[o] = S;
    }
}

// ---------------------------------------------------------------- combine chunk partials -> per-token logp
__global__ __launch_bounds__(256) void lse_reduce(const float* __restrict__ pM,
                                                  const float* __restrict__ pS,
                                                  const float* __restrict__ tokL,
                                                  const int* __restrict__ y,
                                                  float* __restrict__ logp) {
    int g = blockIdx.x * 256 + threadIdx.x;
    if (g >= 2 * NTOK) return;
    int model = g >> 11;
    int token = g & (NTOK - 1);
    float M = -1e30f, S = 0.f;
    for (int c = 0; c < NCHUNK; ++c) {
        size_t o = ((size_t)model * NCHUNK + c) * NTOK + token;
        float m = pM[o], s = pS[o];
        if (m > M) { S = S * __expf(M - m) + s; M = m; }
        else       { S += s * __expf(m - M); }
    }
    float lse = M + logf(S);
    int t = y[token];
    logp[g] = (t == IGNORE_INDEX) ? 0.f : (tokL[g] - lse);
}

// ---------------------------------------------------------------- final KTO scalar
__device__ __forceinline__ float sigf(float z) { return 1.f / (1.f + expf(-z)); }

__global__ void final_loss(const float* __restrict__ logp,
                           const int* __restrict__ y,
                           float* __restrict__ out) {
    int lane = threadIdx.x;  // 64 threads, one wave
    float avg[2][4];
    for (int model = 0; model < 2; ++model)
        for (int b = 0; b < 4; ++b) {
            float s = 0.f, c = 0.f;
            for (int t = lane; t < T_DIM; t += 64) {
                int token = b * T_DIM + t;
                if (y[token] != IGNORE_INDEX) { s += logp[model * NTOK + token]; c += 1.f; }
            }
            for (int m = 1; m < 64; m <<= 1) {
                s += __shfl_xor(s, m, 64);
                c += __shfl_xor(c, m, 64);
            }
            avg[model][b] = s / c;
        }
    if (lane == 0) {
        float loss = 0.f;
        for (int b = 0; b < 2; ++b) {                    // chosen
            float lr = avg[0][b] - avg[1][b];
            loss += 1.f - sigf(BETA * lr);
        }
        for (int b = 2; b < 4; ++b) {                    // rejected
            float lr = avg[0][b] - avg[1][b];
            loss += 1.f - sigf(-BETA * lr);
        }
        out[0] = loss * 0.5f;                            // / half (half = 2)
    }
}

// ---------------------------------------------------------------- launch
extern "C" void kernel_launch(void* const* d_in, const int* in_sizes, int n_in,
                              void* d_out, int out_size, void* d_ws, size_t ws_size,
                              hipStream_t stream) {
    const float* x  = (const float*)d_in[0];
    const float* rx = (const float*)d_in[1];
    const int*   y  = (const int*)d_in[2];
    const float* W  = (const float*)d_in[3];
    const float* rW = (const float*)d_in[4];
    float* out = (float*)d_out;

    const size_t nX = (size_t)NTOK * H_DIM;   // 4,194,304
    const size_t nW = (size_t)V_DIM * H_DIM;  // 65,536,000

    char* p = (char*)d_ws;
    float* pM   = (float*)p; p += (size_t)2 * NCHUNK * NTOK * 4;
    float* pS   = (float*)p; p += (size_t)2 * NCHUNK * NTOK * 4;
    float* tokL = (float*)p; p += (size_t)2 * NTOK * 4;
    float* logp = (float*)p; p += (size_t)2 * NTOK * 4;
    size_t base = (size_t)(p - (char*)d_ws);
    size_t need_fast = base + 2 * nX * 2 + 2 * nW * 2;

    dim3 grid(NTILE, NCHUNK, 2);
    if (ws_size >= need_fast) {
        f16* xb  = (f16*)p; p += nX * 2;
        f16* rxb = (f16*)p; p += nX * 2;
        f16* wb  = (f16*)p; p += nW * 2;
        f16* rwb = (f16*)p; p += nW * 2;
        cvt_f32_f16<<<(int)(nX / 8 / 256), 256, 0, stream>>>(x,  xb,  (int)nX);
        cvt_f32_f16<<<(int)(nX / 8 / 256), 256, 0, stream>>>(rx, rxb, (int)nX);
        cvt_f32_f16<<<(int)(nW / 8 / 256), 256, 0, stream>>>(W,  wb,  (int)nW);
        cvt_f32_f16<<<(int)(nW / 8 / 256), 256, 0, stream>>>(rW, rwb, (int)nW);
        gemm_lse<true><<<grid, 256, 0, stream>>>(xb, rxb, wb, rwb, y, pM, pS, tokL);
    } else {
        gemm_lse<false><<<grid, 256, 0, stream>>>(x, rx, W, rW, y, pM, pS, tokL);
    }
    lse_reduce<<<16, 256, 0, stream>>>(pM, pS, tokL, y, logp);
    final_loss<<<1, 64, 0, stream>>>(logp, y, out);
}

// Round 3
// 1561.373 us; speedup vs baseline: 3.7631x; 1.2166x over previous
//
#include <hip/hip_runtime.h>
#include <stdint.h>

// Problem constants (from reference)
#define B_DIM 4
#define T_DIM 512
#define NTOK  2048          // B*T
#define H_DIM 2048
#define V_DIM 32000
#define TM    128
#define TN    128
#define BK    64            // two 32-deep MFMA phases per barrier pair
#define NCHUNK (V_DIM / TN) // 250
#define NTILE  (NTOK / TM)  // 16
#define BETA   0.1f
#define IGNORE_INDEX (-100)

typedef _Float16 f16;
typedef _Float16 half8 __attribute__((ext_vector_type(8)));
typedef float    f32x4 __attribute__((ext_vector_type(4)));

// ---------------------------------------------------------------- fp32 -> fp16
__global__ __launch_bounds__(256) void cvt_f32_f16(const float* __restrict__ src,
                                                   f16* __restrict__ dst, int n) {
    int i = (blockIdx.x * 256 + threadIdx.x) * 8;
    if (i + 8 > n) return;
    float4 v0 = *(const float4*)(src + i);
    float4 v1 = *(const float4*)(src + i + 4);
    half8 h = { (f16)v0.x, (f16)v0.y, (f16)v0.z, (f16)v0.w,
                (f16)v1.x, (f16)v1.y, (f16)v1.z, (f16)v1.w };
    *(half8*)(dst + i) = h;
}

// ---------------------------------------------------------------- GEMM + online LSE partials
// C[m][n] = sum_k X[m][k] * W[n][k]   (NT gemm, both row-major, K contiguous)
// LDS tile layout: [kchunk(8)][row(128)][8 halves]; fragment reads by a quad
// group touch 16 contiguous 16B cells (bank-conflict-free, verified R2).
// BK=64: 32 barrier pairs instead of 64 — halves the vmcnt(0) drain count
// (the dominant stall: W is 262MB, loads are HBM-latency).
template <bool DIRECT>
__global__ __launch_bounds__(256, 3) void gemm_lse(
    const void* __restrict__ x0, const void* __restrict__ x1,
    const void* __restrict__ w0, const void* __restrict__ w1,
    const int* __restrict__ y,
    float2* __restrict__ pMS,
    float* __restrict__ tokL)
{
    const int tile  = blockIdx.x;   // 0..15  (fastest: 16 tiles share one W chunk in LLC)
    const int chunk = blockIdx.y;   // 0..249
    const int model = blockIdx.z;   // 0..1
    const void* Xp = model ? x1 : x0;
    const void* Wp = model ? w1 : w0;

    const int tid  = threadIdx.x;
    const int lane = tid & 63;
    const int wave = tid >> 6;
    const int wm   = wave >> 1;     // 0..1: which 64-row half (tokens)
    const int wn   = wave & 1;      // 0..1: which 64-col half (vocab)

    __shared__ __align__(16) f16 As[8][TM][8];  // 16 KB  [kchunk][row][8]
    __shared__ __align__(16) f16 Bs[8][TN][8];  // 16 KB
    __shared__ float redM[TM][2];
    __shared__ float redS[TM][2];
    __shared__ int   ys[TM];

    if (tid < TM) ys[tid] = y[tile * TM + tid];

    f32x4 acc[4][4];
#pragma unroll
    for (int i = 0; i < 4; ++i)
#pragma unroll
        for (int j = 0; j < 4; ++j) acc[i][j] = (f32x4){0.f, 0.f, 0.f, 0.f};

    const int rowA0 = tile * TM;
    const int rowB0 = chunk * TN;
    const int kc    = lane >> 4;    // k-chunk (0..3) within a 32-deep phase

    // Staging map: load i covers LDS slot idx=i*256+tid -> chunk c=idx>>7, row r=idx&127.
    // r = tid&127 is i-invariant; c = i*2 + (tid>>7). So one base pointer per
    // matrix + constant immediate offsets (i*16 halves src, i*2048 halves dst).
    const int rS = tid & 127;
    const int cS = tid >> 7;

    if (DIRECT) {
        const f16* pA = (const f16*)Xp + (size_t)(rowA0 + rS) * H_DIM + cS * 8;
        const f16* pB = (const f16*)Wp + (size_t)(rowB0 + rS) * H_DIM + cS * 8;
        f16* dA = &As[0][0][0] + tid * 8;
        f16* dB = &Bs[0][0][0] + tid * 8;

        for (int k0 = 0; k0 < H_DIM; k0 += BK) {
#pragma unroll
            for (int i = 0; i < 4; ++i)
                __builtin_amdgcn_global_load_lds(
                    (const __attribute__((address_space(1))) unsigned int*)(pA + i * 16),
                    (__attribute__((address_space(3))) unsigned int*)(dA + i * 2048),
                    16, 0, 0);
#pragma unroll
            for (int i = 0; i < 4; ++i)
                __builtin_amdgcn_global_load_lds(
                    (const __attribute__((address_space(1))) unsigned int*)(pB + i * 16),
                    (__attribute__((address_space(3))) unsigned int*)(dB + i * 2048),
                    16, 0, 0);
            pA += BK; pB += BK;
            __syncthreads();

#pragma unroll
            for (int p = 0; p < 2; ++p) {
                half8 af[4], bfr[4];
#pragma unroll
                for (int i = 0; i < 4; ++i)
                    af[i] = *(const half8*)As[p * 4 + kc][wm * 64 + i * 16 + (lane & 15)];
#pragma unroll
                for (int j = 0; j < 4; ++j)
                    bfr[j] = *(const half8*)Bs[p * 4 + kc][wn * 64 + j * 16 + (lane & 15)];
#pragma unroll
                for (int i = 0; i < 4; ++i)
#pragma unroll
                    for (int j = 0; j < 4; ++j)
                        acc[i][j] = __builtin_amdgcn_mfma_f32_16x16x32_f16(af[i], bfr[j], acc[i][j], 0, 0, 0);
            }
            __syncthreads();
        }
    } else {
        const float* pA = (const float*)Xp + (size_t)(rowA0 + rS) * H_DIM + cS * 8;
        const float* pB = (const float*)Wp + (size_t)(rowB0 + rS) * H_DIM + cS * 8;
        f16* dA = &As[0][0][0] + tid * 8;
        f16* dB = &Bs[0][0][0] + tid * 8;

        for (int k0 = 0; k0 < H_DIM; k0 += BK) {
#pragma unroll
            for (int i = 0; i < 4; ++i) {
                float4 v0 = *(const float4*)(pA + i * 16);
                float4 v1 = *(const float4*)(pA + i * 16 + 4);
                half8 h = { (f16)v0.x, (f16)v0.y, (f16)v0.z, (f16)v0.w,
                            (f16)v1.x, (f16)v1.y, (f16)v1.z, (f16)v1.w };
                *(half8*)(dA + i * 2048) = h;
            }
#pragma unroll
            for (int i = 0; i < 4; ++i) {
                float4 v0 = *(const float4*)(pB + i * 16);
                float4 v1 = *(const float4*)(pB + i * 16 + 4);
                half8 h = { (f16)v0.x, (f16)v0.y, (f16)v0.z, (f16)v0.w,
                            (f16)v1.x, (f16)v1.y, (f16)v1.z, (f16)v1.w };
                *(half8*)(dB + i * 2048) = h;
            }
            pA += BK; pB += BK;
            __syncthreads();

#pragma unroll
            for (int p = 0; p < 2; ++p) {
                half8 af[4], bfr[4];
#pragma unroll
                for (int i = 0; i < 4; ++i)
                    af[i] = *(const half8*)As[p * 4 + kc][wm * 64 + i * 16 + (lane & 15)];
#pragma unroll
                for (int j = 0; j < 4; ++j)
                    bfr[j] = *(const half8*)Bs[p * 4 + kc][wn * 64 + j * 16 + (lane & 15)];
#pragma unroll
                for (int i = 0; i < 4; ++i)
#pragma unroll
                    for (int j = 0; j < 4; ++j)
                        acc[i][j] = __builtin_amdgcn_mfma_f32_16x16x32_f16(af[i], bfr[j], acc[i][j], 0, 0, 0);
            }
            __syncthreads();
        }
    }

    // ---- epilogue ----
    // C/D layout: col = lane&15 (vocab), row = (lane>>4)*4 + reg (token)
    // 1) target logit — ALL acc indices compile-time constant (R1 scratch bug)
#pragma unroll
    for (int i = 0; i < 4; ++i) {
#pragma unroll
        for (int r = 0; r < 4; ++r) {
            int rl = wm * 64 + i * 16 + ((lane >> 4) << 2) + r;
            int t = ys[rl];
            int trel = t - (rowB0 + wn * 64);
#pragma unroll
            for (int j = 0; j < 4; ++j) {
                if (trel == j * 16 + (lane & 15))
                    tokL[model * NTOK + rowA0 + rl] = acc[i][j][r];
            }
        }
    }

    // 2) per-row (max, sumexp) over this wave's 64 columns, then combine halves
#pragma unroll
    for (int i = 0; i < 4; ++i) {
#pragma unroll
        for (int r = 0; r < 4; ++r) {
            float mx = fmaxf(fmaxf(acc[i][0][r], acc[i][1][r]),
                             fmaxf(acc[i][2][r], acc[i][3][r]));
            for (int m = 1; m < 16; m <<= 1) mx = fmaxf(mx, __shfl_xor(mx, m, 64));
            float s = 0.f;
#pragma unroll
            for (int j = 0; j < 4; ++j) s += __expf(acc[i][j][r] - mx);
            for (int m = 1; m < 16; m <<= 1) s += __shfl_xor(s, m, 64);
            if ((lane & 15) == 0) {
                int rl = wm * 64 + i * 16 + ((lane >> 4) << 2) + r;
                redM[rl][wn] = mx;
                redS[rl][wn] = s;
            }
        }
    }
    __syncthreads();
    if (tid < TM) {
        float m0 = redM[tid][0], m1 = redM[tid][1];
        float s0 = redS[tid][0], s1 = redS[tid][1];
        float M = fmaxf(m0, m1);
        float S = s0 * __expf(m0 - M) + s1 * __expf(m1 - M);
        // transposed partials: [model][token][chunk] for coalesced lse_reduce
        size_t o = ((size_t)model * NTOK + rowA0 + tid) * NCHUNK + chunk;
        pMS[o] = make_float2(M, S);
    }
}

// ---------------------------------------------------------------- combine chunk partials -> per-token logp
// One wave per (model,token): coalesced 2KB read + wave-level LSE merge.
__global__ __launch_bounds__(256) void lse_reduce(const float2* __restrict__ pMS,
                                                  const float* __restrict__ tokL,
                                                  const int* __restrict__ y,
                                                  float* __restrict__ logp) {
    int g = blockIdx.x * 4 + (threadIdx.x >> 6);   // 0..4095 = model*NTOK + token
    int lane = threadIdx.x & 63;
    const float2* base = pMS + (size_t)g * NCHUNK;
    float M = -1e30f, S = 0.f;
    for (int c = lane; c < NCHUNK; c += 64) {
        float2 ms = base[c];
        if (ms.x > M) { S = S * __expf(M - ms.x) + ms.y; M = ms.x; }
        else          { S += ms.y * __expf(ms.x - M); }
    }
#pragma unroll
    for (int off = 1; off < 64; off <<= 1) {
        float Mo = __shfl_xor(M, off, 64);
        float So = __shfl_xor(S, off, 64);
        float Mn = fmaxf(M, Mo);
        S = S * __expf(M - Mn) + So * __expf(Mo - Mn);
        M = Mn;
    }
    if (lane == 0) {
        float lse = M + logf(S);
        int token = g & (NTOK - 1);
        int t = y[token];
        logp[g] = (t == IGNORE_INDEX) ? 0.f : (tokL[g] - lse);
    }
}

// ---------------------------------------------------------------- final KTO scalar
__device__ __forceinline__ float sigf(float z) { return 1.f / (1.f + expf(-z)); }

__global__ void final_loss(const float* __restrict__ logp,
                           const int* __restrict__ y,
                           float* __restrict__ out) {
    int lane = threadIdx.x;  // 64 threads, one wave
    float avg[2][4];
    for (int model = 0; model < 2; ++model)
        for (int b = 0; b < 4; ++b) {
            float s = 0.f, c = 0.f;
            for (int t = lane; t < T_DIM; t += 64) {
                int token = b * T_DIM + t;
                if (y[token] != IGNORE_INDEX) { s += logp[model * NTOK + token]; c += 1.f; }
            }
            for (int m = 1; m < 64; m <<= 1) {
                s += __shfl_xor(s, m, 64);
                c += __shfl_xor(c, m, 64);
            }
            avg[model][b] = s / c;
        }
    if (lane == 0) {
        float loss = 0.f;
        for (int b = 0; b < 2; ++b) {                    // chosen
            float lr = avg[0][b] - avg[1][b];
            loss += 1.f - sigf(BETA * lr);
        }
        for (int b = 2; b < 4; ++b) {                    // rejected
            float lr = avg[0][b] - avg[1][b];
            loss += 1.f - sigf(-BETA * lr);
        }
        out[0] = loss * 0.5f;                            // / half (half = 2)
    }
}

// ---------------------------------------------------------------- launch
extern "C" void kernel_launch(void* const* d_in, const int* in_sizes, int n_in,
                              void* d_out, int out_size, void* d_ws, size_t ws_size,
                              hipStream_t stream) {
    const float* x  = (const float*)d_in[0];
    const float* rx = (const float*)d_in[1];
    const int*   y  = (const int*)d_in[2];
    const float* W  = (const float*)d_in[3];
    const float* rW = (const float*)d_in[4];
    float* out = (float*)d_out;

    const size_t nX = (size_t)NTOK * H_DIM;   // 4,194,304
    const size_t nW = (size_t)V_DIM * H_DIM;  // 65,536,000

    char* p = (char*)d_ws;
    float2* pMS = (float2*)p; p += (size_t)2 * NTOK * NCHUNK * 8;   // 16.4 MB
    float* tokL = (float*)p;  p += (size_t)2 * NTOK * 4;
    float* logp = (float*)p;  p += (size_t)2 * NTOK * 4;
    size_t base = (size_t)(p - (char*)d_ws);
    size_t need_fast = base + 2 * nX * 2 + 2 * nW * 2;

    dim3 grid(NTILE, NCHUNK, 2);
    if (ws_size >= need_fast) {
        f16* xb  = (f16*)p; p += nX * 2;
        f16* rxb = (f16*)p; p += nX * 2;
        f16* wb  = (f16*)p; p += nW * 2;
        f16* rwb = (f16*)p; p += nW * 2;
        cvt_f32_f16<<<(int)(nX / 8 / 256), 256, 0, stream>>>(x,  xb,  (int)nX);
        cvt_f32_f16<<<(int)(nX / 8 / 256), 256, 0, stream>>>(rx, rxb, (int)nX);
        cvt_f32_f16<<<(int)(nW / 8 / 256), 256, 0, stream>>>(W,  wb,  (int)nW);
        cvt_f32_f16<<<(int)(nW / 8 / 256), 256, 0, stream>>>(rW, rwb, (int)nW);
        gemm_lse<true><<<grid, 256, 0, stream>>>(xb, rxb, wb, rwb, y, pMS, tokL);
    } else {
        gemm_lse<false><<<grid, 256, 0, stream>>>(x, rx, W, rW, y, pMS, tokL);
    }
    lse_reduce<<<1024, 256, 0, stream>>>(pMS, tokL, y, logp);
    final_loss<<<1, 64, 0, stream>>>(logp, y, out);
}